// Round 10
// baseline (431.955 us; speedup 1.0000x reference)
//
#include <hip/hip_runtime.h>
#include <cstdint>
#include <cstddef>

// Problem constants
#define B_ 4
#define S_ 2048
#define E_ 1024
#define H_ 16
#define D_ 64
#define M_ (B_*S_)                        // 8192 tokens
#define NE_ ((size_t)B_*H_*S_*D_)         // 8388608 elements per q/k/v buffer

typedef unsigned int  u32;
typedef unsigned short u16;
typedef __attribute__((ext_vector_type(8))) short bf16x8;
typedef __attribute__((ext_vector_type(4))) float f32x4;
typedef __attribute__((ext_vector_type(2))) unsigned int u32x2;

// fp32 -> bf16 (round-to-nearest-even), finite inputs
__device__ __forceinline__ u16 f2bf(float x) {
    u32 u = __float_as_uint(x);
    u32 r = (u + 0x7FFFu + ((u >> 16) & 1u)) >> 16;
    return (u16)r;
}
__device__ __forceinline__ float bf2f(u16 h) { return __uint_as_float((u32)h << 16); }

// packed fp32x2 -> bf16x2 (RNE), single VOP3 instruction (T12 recipe)
__device__ __forceinline__ u32 cvtpk_bf16(float lo, float hi) {
    u32 r;
    asm("v_cvt_pk_bf16_f32 %0, %1, %2" : "=v"(r) : "v"(lo), "v"(hi));
    return r;
}

// async global->LDS 16B DMA: per-lane global addr, wave-uniform LDS base;
// HW writes lane i at ldsbase + i*16 (linear).
__device__ __forceinline__ void gload_lds16(const void* gsrc, void* lds) {
    __builtin_amdgcn_global_load_lds(
        (const __attribute__((address_space(1))) u32*)gsrc,
        (__attribute__((address_space(3))) u32*)lds, 16, 0, 0);
}

// ---------------------------------------------------------------------------
// TWO image formats:
//
// k64 tile (64x64, 8 KB) -- used for K and V (attn kernel):
//   offset = r*64 + ((c ^ (r&7))<<3) + (k&7),  c = k>>3.
//
// k32 tile (64 rows x 32 k, 4 KB) -- used for all GEMM operands
// (x, w_qkv, w_proj, o). BK=32 GEMM K-step:
//   l = r>>1,  s = (r&1)*4 + (k>>3),  ph = s ^ (l&7)
//   offset = l*64 + ph*8 + (k&7)
// Image array: [row-tile][k-tile(32, K=1024)] -> tile idx = rt*32+kt.
// ---------------------------------------------------------------------------

// ---------------------------------------------------------------------------
// convert fp32 matrix (rows x 1024, row-major) -> hi/lo k32 images.
// one block per 4 KB tile; blockIdx.x = rt*32 + kt. Linear 16B writes.
// ---------------------------------------------------------------------------
__global__ __launch_bounds__(256)
void convert_img(const float* __restrict__ src, u16* __restrict__ dh, u16* __restrict__ dl)
{
    const int tile = blockIdx.x;
    const int rt = tile >> 5, kt = tile & 31;
    const size_t tb = (size_t)tile * 2048;         // u16 elements
    const int ci = threadIdx.x;                    // 0..255, 8 el each
    const int l  = ci >> 3;                        // line 0..31
    const int ph = ci & 7;                         // phys slot
    const int s  = ph ^ (l & 7);                   // logical slot
    const int r  = (l << 1) | (s >> 2);            // source row in tile
    const int k0 = (s & 3) << 3;                   // source k base
    const float* sp = src + ((size_t)(rt * 64 + r)) * 1024 + kt * 32 + k0;
    const float4 f0 = *(const float4*)sp;
    const float4 f1 = *(const float4*)(sp + 4);
    const float vals[8] = {f0.x, f0.y, f0.z, f0.w, f1.x, f1.y, f1.z, f1.w};
    __align__(16) short hs[8];
    __align__(16) short ls[8];
    #pragma unroll
    for (int j = 0; j < 8; ++j) {
        const u16 h = f2bf(vals[j]);
        hs[j] = (short)h;
        ls[j] = (short)f2bf(vals[j] - bf2f(h));
    }
    *(bf16x8*)(dh + tb + ci * 8) = *(const bf16x8*)hs;
    *(bf16x8*)(dl + tb + ci * 8) = *(const bf16x8*)ls;
}

// ---------------------------------------------------------------------------
// QKV GEMM -- UNCHANGED from round 9 (its best config: 128^2, BK=32, 4 waves,
// dbuf 64 KB, 2 blocks/CU, DMA-first, one barrier per K-tile, no swizzle).
// ---------------------------------------------------------------------------
__global__ __launch_bounds__(256, 2)
void gemm_qkv(const u16* __restrict__ AIh, const u16* __restrict__ AIl,
              const u16* __restrict__ BIh, const u16* __restrict__ BIl,
              const float* __restrict__ bias,
              u16* __restrict__ qh, u16* __restrict__ ql,
              u16* __restrict__ kh,
              u16* __restrict__ vh, u16* __restrict__ vl)
{
    __shared__ __align__(16) u16 sT[2][8][2048];   // 64 KB

    const int tid = threadIdx.x, lane = tid & 63, w = tid >> 6;  // 4 waves
    const int quad = lane >> 4, l15 = lane & 15;
    const int bx = blockIdx.x, by = blockIdx.y;
    const int m0  = bx * 128;
    const int n0  = by * 128;
    const int mt0 = bx * 2;                        // A row-tile base (64-row)
    const int nt0 = by * 2;                        // B row-tile base
    const int rw  = w >> 1;                        // 0..1: wave's 64-row slab
    const int cw  = w & 1;                         // 0..1: wave's 64-col slab

    const u16* srcq[8];
    #pragma unroll
    for (int it = 0; it < 8; ++it) {
        const int g = w * 8 + it;
        const int t = g >> 2, qtr = g & 3;
        const u16* img = (t < 2) ? AIh : (t < 4) ? AIl : (t < 6) ? BIh : BIl;
        const int rtile = ((t < 4) ? mt0 : nt0) + (t & 1);
        srcq[it] = img + (size_t)rtile * (32 * 2048) + qtr * 512 + lane * 8;
    }

    f32x4 acc[4][4];
    #pragma unroll
    for (int i = 0; i < 4; ++i)
        #pragma unroll
        for (int j = 0; j < 4; ++j)
            acc[i][j] = (f32x4){0.f, 0.f, 0.f, 0.f};

    // prologue: stage K-tile 0 into buffer 0
    #pragma unroll
    for (int it = 0; it < 8; ++it)
        gload_lds16(srcq[it], (char*)&sT[0][0][0] + (w * 8 + it) * 1024);
    __syncthreads();

    #pragma unroll 2
    for (int kt = 0; kt < 32; ++kt) {
        const int cur = kt & 1;
        if (kt < 31) {
            #pragma unroll
            for (int it = 0; it < 8; ++it)
                gload_lds16(srcq[it] + (size_t)(kt + 1) * 2048,
                            (char*)&sT[cur ^ 1][0][0] + (w * 8 + it) * 1024);
        }
        bf16x8 aH[4], aL[4], bH[4], bL[4];
        #pragma unroll
        for (int i = 0; i < 4; ++i) {
            const int r = i * 16 + l15, l = r >> 1;
            const int off = l * 64 + (((((r & 1) << 2) + quad) ^ (l & 7)) << 3);
            aH[i] = *(const bf16x8*)&sT[cur][rw][off];
            aL[i] = *(const bf16x8*)&sT[cur][2 + rw][off];
        }
        #pragma unroll
        for (int j = 0; j < 4; ++j) {
            const int r = j * 16 + l15, l = r >> 1;
            const int off = l * 64 + (((((r & 1) << 2) + quad) ^ (l & 7)) << 3);
            bH[j] = *(const bf16x8*)&sT[cur][4 + cw][off];
            bL[j] = *(const bf16x8*)&sT[cur][6 + cw][off];
        }
        __builtin_amdgcn_s_setprio(1);
        #pragma unroll
        for (int i = 0; i < 4; ++i)
            #pragma unroll
            for (int j = 0; j < 4; ++j) {
                acc[i][j] = __builtin_amdgcn_mfma_f32_16x16x32_bf16(aL[i], bH[j], acc[i][j], 0, 0, 0);
                acc[i][j] = __builtin_amdgcn_mfma_f32_16x16x32_bf16(aH[i], bL[j], acc[i][j], 0, 0, 0);
                acc[i][j] = __builtin_amdgcn_mfma_f32_16x16x32_bf16(aH[i], bH[j], acc[i][j], 0, 0, 0);
            }
        __builtin_amdgcn_s_setprio(0);
        __syncthreads();
    }

    // ---- epilogue (q natural+scaled; k hi-only k64 image; v k64 image) ----
    const int fbase = n0 + cw * 64;                // 64-aligned
    float bj[4];
    #pragma unroll
    for (int j = 0; j < 4; ++j) bj[j] = bias[fbase + j * 16 + l15];

    const int cR = fbase >> 10;                    // 0=q 1=k 2=v (uniform per wave)
    const int hh = (fbase >> 6) & 15;
    #pragma unroll
    for (int i = 0; i < 4; ++i)
        #pragma unroll
        for (int j = 0; j < 4; ++j)
            #pragma unroll
            for (int reg = 0; reg < 4; ++reg) {
                float val = acc[i][j][reg] + bj[j];
                const int m = m0 + rw * 64 + i * 16 + quad * 4 + reg;
                const int d = j * 16 + l15;
                const int bb = m >> 11, s = m & 2047;
                const int bh = bb * 16 + hh;
                // q scale = 0.125 * log2(e): softmax uses exp2 directly.
                if (cR == 0) val *= 0.18033688011112042f;
                const u16 h = f2bf(val);
                if (cR == 0) {
                    const u16 lo = f2bf(val - bf2f(h));
                    const size_t idx = ((size_t)bh * 2048 + s) * 64 + d;
                    qh[idx] = h; ql[idx] = lo;
                } else if (cR == 1) {
                    // k-lo not consumed (2-product QK) -> only hi written (k64 image)
                    const size_t tile = (size_t)bh * 32 + (s >> 6);
                    const int r = s & 63;
                    const size_t off = (tile << 12) + r * 64 + (((d >> 3) ^ (r & 7)) << 3) + (d & 7);
                    kh[off] = h;
                } else {
                    const u16 lo = f2bf(val - bf2f(h));
                    const size_t tile = (size_t)bh * 32 + (s >> 6);
                    const size_t off = (tile << 12) + d * 64 + ((((s & 63) >> 3) ^ (d & 7)) << 3) + (s & 7);
                    vh[off] = h; vl[off] = lo;
                }
            }
}

// ---------------------------------------------------------------------------
// proj GEMM (round 10): SAME 128^2/dbuf/2-blocks-per-CU structure that won
// for QKV (replaces the 256x128 8-wave 1-block/CU r9 config). Grid 64x8 =
// 512 blocks = exactly 2 rounds... 2 blocks/CU co-resident cover each
// other's barrier drains. Plain fp32+bias epilogue.
// ---------------------------------------------------------------------------
__global__ __launch_bounds__(256, 2)
void gemm_proj(const u16* __restrict__ AIh, const u16* __restrict__ AIl,
               const u16* __restrict__ BIh, const u16* __restrict__ BIl,
               const float* __restrict__ bias, float* __restrict__ Cout)
{
    __shared__ __align__(16) u16 sT[2][8][2048];   // 64 KB

    const int tid = threadIdx.x, lane = tid & 63, w = tid >> 6;  // 4 waves
    const int quad = lane >> 4, l15 = lane & 15;
    const int bx = blockIdx.x, by = blockIdx.y;
    const int m0  = bx * 128;
    const int n0  = by * 128;
    const int mt0 = bx * 2;
    const int nt0 = by * 2;
    const int rw  = w >> 1;
    const int cw  = w & 1;

    const u16* srcq[8];
    #pragma unroll
    for (int it = 0; it < 8; ++it) {
        const int g = w * 8 + it;
        const int t = g >> 2, qtr = g & 3;
        const u16* img = (t < 2) ? AIh : (t < 4) ? AIl : (t < 6) ? BIh : BIl;
        const int rtile = ((t < 4) ? mt0 : nt0) + (t & 1);
        srcq[it] = img + (size_t)rtile * (32 * 2048) + qtr * 512 + lane * 8;
    }

    f32x4 acc[4][4];
    #pragma unroll
    for (int i = 0; i < 4; ++i)
        #pragma unroll
        for (int j = 0; j < 4; ++j)
            acc[i][j] = (f32x4){0.f, 0.f, 0.f, 0.f};

    #pragma unroll
    for (int it = 0; it < 8; ++it)
        gload_lds16(srcq[it], (char*)&sT[0][0][0] + (w * 8 + it) * 1024);
    __syncthreads();

    #pragma unroll 2
    for (int kt = 0; kt < 32; ++kt) {
        const int cur = kt & 1;
        if (kt < 31) {
            #pragma unroll
            for (int it = 0; it < 8; ++it)
                gload_lds16(srcq[it] + (size_t)(kt + 1) * 2048,
                            (char*)&sT[cur ^ 1][0][0] + (w * 8 + it) * 1024);
        }
        bf16x8 aH[4], aL[4], bH[4], bL[4];
        #pragma unroll
        for (int i = 0; i < 4; ++i) {
            const int r = i * 16 + l15, l = r >> 1;
            const int off = l * 64 + (((((r & 1) << 2) + quad) ^ (l & 7)) << 3);
            aH[i] = *(const bf16x8*)&sT[cur][rw][off];
            aL[i] = *(const bf16x8*)&sT[cur][2 + rw][off];
        }
        #pragma unroll
        for (int j = 0; j < 4; ++j) {
            const int r = j * 16 + l15, l = r >> 1;
            const int off = l * 64 + (((((r & 1) << 2) + quad) ^ (l & 7)) << 3);
            bH[j] = *(const bf16x8*)&sT[cur][4 + cw][off];
            bL[j] = *(const bf16x8*)&sT[cur][6 + cw][off];
        }
        __builtin_amdgcn_s_setprio(1);
        #pragma unroll
        for (int i = 0; i < 4; ++i)
            #pragma unroll
            for (int j = 0; j < 4; ++j) {
                acc[i][j] = __builtin_amdgcn_mfma_f32_16x16x32_bf16(aL[i], bH[j], acc[i][j], 0, 0, 0);
                acc[i][j] = __builtin_amdgcn_mfma_f32_16x16x32_bf16(aH[i], bL[j], acc[i][j], 0, 0, 0);
                acc[i][j] = __builtin_amdgcn_mfma_f32_16x16x32_bf16(aH[i], bH[j], acc[i][j], 0, 0, 0);
            }
        __builtin_amdgcn_s_setprio(0);
        __syncthreads();
    }

    const int fbase = n0 + cw * 64;
    float bj[4];
    #pragma unroll
    for (int j = 0; j < 4; ++j) bj[j] = bias[fbase + j * 16 + l15];
    #pragma unroll
    for (int i = 0; i < 4; ++i)
        #pragma unroll
        for (int j = 0; j < 4; ++j)
            #pragma unroll
            for (int reg = 0; reg < 4; ++reg) {
                const int m = m0 + rw * 64 + i * 16 + quad * 4 + reg;
                const int f = fbase + j * 16 + l15;
                Cout[(size_t)m * 1024 + f] = acc[i][j][reg] + bj[j];
            }
}

// ---------------------------------------------------------------------------
// MFMA flash attention (round 10): compute core UNCHANGED (verified r4-r9).
// Two structural changes:
//  1. XCD-chunked bh-grouped block swizzle: 1D grid 1024; HW round-robins
//     consecutive blockIdx across the 8 XCDs, so flat = j*8 + c places
//     logical block (c*128 + j) on XCD c -> XCD c owns bh in [8c, 8c+8)
//     COMPLETE (all 16 q-chunks). Per-XCD-L2 K/V working set drops from
//     "slices of all 64 bh" (~6+ MB) to ~4 bh x 768 KB (~3 MB < 4 MB L2);
//     the 16 blocks sharing a bh stage the same K-tiles as L2 hits.
//     Bijective (1024 % 8 == 0).
//  2. KV double-buffer (24 -> 48 KB, still 3 blocks/CU: 48x3=144<=160;
//     round-1's dbuf failure was the Psh-era 66 KB -> lost block). One
//     barrier per K-tile: issue kt+1 DMA -> compute kt -> __syncthreads
//     (its implicit vmcnt(0) drains the prefetch; WAR on buf^1 is proven
//     by the previous barrier).
// ---------------------------------------------------------------------------
__global__ __launch_bounds__(256, 3)
void attn_mfma(const u16* __restrict__ qh, const u16* __restrict__ ql,
               const u16* __restrict__ kh,
               const u16* __restrict__ vh, const u16* __restrict__ vl,
               u16* __restrict__ oh, u16* __restrict__ ol)
{
    __shared__ __align__(16) u16 KV[2][3][4096];  // dbuf x {Khi Vthi Vtlo} 48 KB

    const int tid  = threadIdx.x;
    const int lane = tid & 63, w = tid >> 6;
    const int quad = lane >> 4, l15 = lane & 15;

    // XCD swizzle: flat = j*8 + c  ->  logical = c*128 + j
    const int flat = blockIdx.x;
    const int logical = (flat & 7) * 128 + (flat >> 3);
    const int bh = logical >> 4;                  // 0..63
    const int q0 = (logical & 15) * 128 + w * 32; // q-chunk * 128

    bf16x8 Qf[2][2][2];
    #pragma unroll
    for (int qs = 0; qs < 2; ++qs)
        #pragma unroll
        for (int kk = 0; kk < 2; ++kk) {
            const size_t idx = ((size_t)bh * S_ + q0 + qs * 16 + l15) * 64 + kk * 32 + quad * 8;
            Qf[qs][kk][0] = *(const bf16x8*)(qh + idx);
            Qf[qs][kk][1] = *(const bf16x8*)(ql + idx);
        }

    f32x4 O[2][4];
    float l_part[2] = {0.f, 0.f};
    #pragma unroll
    for (int qs = 0; qs < 2; ++qs)
        #pragma unroll
        for (int ds = 0; ds < 4; ++ds)
            O[qs][ds] = (f32x4){0.f, 0.f, 0.f, 0.f};

    const char* gk[3] = {(const char*)kh, (const char*)vh, (const char*)vl};

    // prologue: stage K-tile 0 into buffer 0
    {
        const size_t tb = ((size_t)bh * 32) << 13;
        #pragma unroll
        for (int a = 0; a < 3; ++a)
            #pragma unroll
            for (int it = 0; it < 2; ++it) {
                const int off = w * 2048 + it * 1024;
                gload_lds16(gk[a] + tb + off + lane * 16, (char*)&KV[0][a][0] + off);
            }
    }
    __syncthreads();

    for (int kt = 0; kt < S_ / 64; ++kt) {
        const int cur = kt & 1;

        // issue next-tile DMA into the other buffer (no wait here)
        if (kt < S_ / 64 - 1) {
            const size_t tb = (((size_t)bh * 32 + kt + 1) << 13);
            #pragma unroll
            for (int a = 0; a < 3; ++a)
                #pragma unroll
                for (int it = 0; it < 2; ++it) {
                    const int off = w * 2048 + it * 1024;
                    gload_lds16(gk[a] + tb + off + lane * 16,
                                (char*)&KV[cur ^ 1][a][0] + off);
                }
        }

        // ---- swapped QK:  Ssw[m=k][n=q],  init = -16*log2(e) (fixed max) ----
        f32x4 S[2][4];
        #pragma unroll
        for (int qs = 0; qs < 2; ++qs)
            #pragma unroll
            for (int ks = 0; ks < 4; ++ks)
                S[qs][ks] = (f32x4){-23.083120654223414f, -23.083120654223414f,
                                    -23.083120654223414f, -23.083120654223414f};

        __builtin_amdgcn_s_setprio(1);
        #pragma unroll
        for (int ks = 0; ks < 4; ++ks) {
            const int r = ks * 16 + l15;
            #pragma unroll
            for (int kk = 0; kk < 2; ++kk) {
                const int c = (kk * 4 + quad) ^ (r & 7);
                const bf16x8 Kh = *(const bf16x8*)&KV[cur][0][r * 64 + c * 8];
                #pragma unroll
                for (int qs = 0; qs < 2; ++qs) {
                    S[qs][ks] = __builtin_amdgcn_mfma_f32_16x16x32_bf16(Kh, Qf[qs][kk][1], S[qs][ks], 0, 0, 0);
                    S[qs][ks] = __builtin_amdgcn_mfma_f32_16x16x32_bf16(Kh, Qf[qs][kk][0], S[qs][ks], 0, 0, 0);
                }
            }
        }
        __builtin_amdgcn_s_setprio(0);

        // ---- softmax + in-register transpose to PV operand layout ----
        u32 PA[2][2][4];     // [qs][kk][word]
        #pragma unroll
        for (int qs = 0; qs < 2; ++qs) {
            float lsum = 0.f;
            u32 PK[4][2];
            #pragma unroll
            for (int ks = 0; ks < 4; ++ks) {
                const float p0 = __builtin_exp2f(S[qs][ks][0]);
                const float p1 = __builtin_exp2f(S[qs][ks][1]);
                const float p2 = __builtin_exp2f(S[qs][ks][2]);
                const float p3 = __builtin_exp2f(S[qs][ks][3]);
                lsum += (p0 + p1) + (p2 + p3);
                PK[ks][0] = cvtpk_bf16(p0, p1);
                PK[ks][1] = cvtpk_bf16(p2, p3);
            }
            l_part[qs] += lsum;
            #pragma unroll
            for (int kk = 0; kk < 2; ++kk) {
                const u32x2 t0 = __builtin_amdgcn_permlane32_swap(PK[2 * kk][0], PK[2 * kk + 1][0], false, false);
                const u32x2 w02 = __builtin_amdgcn_permlane16_swap(t0.x, t0.y, false, false);
                const u32x2 t1 = __builtin_amdgcn_permlane32_swap(PK[2 * kk][1], PK[2 * kk + 1][1], false, false);
                const u32x2 w13 = __builtin_amdgcn_permlane16_swap(t1.x, t1.y, false, false);
                PA[qs][kk][0] = w02.x;
                PA[qs][kk][1] = w13.x;
                PA[qs][kk][2] = w02.y;
                PA[qs][kk][3] = w13.y;
            }
        }

        // ---- swapped PV:  O^T += Vt x PA  (two products: Vlo, Vhi) ----
        __builtin_amdgcn_s_setprio(1);
        #pragma unroll
        for (int kk = 0; kk < 2; ++kk) {
            union { u32 w4[4]; bf16x8 v; } pu0, pu1;
            #pragma unroll
            for (int c = 0; c < 4; ++c) { pu0.w4[c] = PA[0][kk][c]; pu1.w4[c] = PA[1][kk][c]; }
            const bf16x8 paf[2] = {pu0.v, pu1.v};
            #pragma unroll
            for (int ds = 0; ds < 4; ++ds) {
                const int r = ds * 16 + l15;
                const int c = (kk * 4 + quad) ^ (r & 7);
                const bf16x8 Vh = *(const bf16x8*)&KV[cur][1][r * 64 + c * 8];
                const bf16x8 Vl = *(const bf16x8*)&KV[cur][2][r * 64 + c * 8];
                #pragma unroll
                for (int qs = 0; qs < 2; ++qs) {
                    O[qs][ds] = __builtin_amdgcn_mfma_f32_16x16x32_bf16(Vl, paf[qs], O[qs][ds], 0, 0, 0);
                    O[qs][ds] = __builtin_amdgcn_mfma_f32_16x16x32_bf16(Vh, paf[qs], O[qs][ds], 0, 0, 0);
                }
            }
        }
        __builtin_amdgcn_s_setprio(0);

        // ONE barrier per tile: implicit vmcnt(0) drains the kt+1 prefetch;
        // also publishes "all waves done reading cur" for the next overwrite.
        __syncthreads();
    }

    // ---- l reduction across quads ----
    float linv[2];
    #pragma unroll
    for (int qs = 0; qs < 2; ++qs) {
        float rs = l_part[qs];
        rs += __shfl_xor(rs, 16);
        rs += __shfl_xor(rs, 32);
        linv[qs] = 1.f / rs;
    }

    // ---- epilogue: lane holds O[d = ds*16+quad*4+reg][q = l15];
    //      write k32 image format (proj GEMM input) ----
    const int bb = bh >> 4, hh = bh & 15;
    #pragma unroll
    for (int qs = 0; qs < 2; ++qs) {
        const float inv = linv[qs];
        const int s = q0 + qs * 16 + l15;
        const int m = bb * 2048 + s;
        const int mt = m >> 6, r = m & 63;
        const int l = r >> 1;
        const size_t tb0 = ((size_t)(mt * 32 + hh * 2)) * 2048;
        #pragma unroll
        for (int ds = 0; ds < 4; ++ds) {
            const int d0 = ds * 16 + quad * 4;     // 4 consecutive d per thread
            const float v0 = O[qs][ds][0] * inv;
            const float v1 = O[qs][ds][1] * inv;
            const float v2 = O[qs][ds][2] * inv;
            const float v3 = O[qs][ds][3] * inv;
            const u32 h01 = cvtpk_bf16(v0, v1);
            const u32 h23 = cvtpk_bf16(v2, v3);
            const float r0 = v0 - bf2f((u16)h01);
            const float r1 = v1 - bf2f((u16)(h01 >> 16));
            const float r2 = v2 - bf2f((u16)h23);
            const float r3 = v3 - bf2f((u16)(h23 >> 16));
            const u32 l01 = cvtpk_bf16(r0, r1);
            const u32 l23 = cvtpk_bf16(r2, r3);
            const int c  = (d0 & 31) >> 3;
            const int ph = (((r & 1) << 2) + c) ^ (l & 7);
            const size_t off = tb0 + (size_t)(d0 >> 5) * 2048 + l * 64 + ph * 8 + (d0 & 7);
            *(u32x2*)(oh + off) = (u32x2){h01, h23};
            *(u32x2*)(ol + off) = (u32x2){l01, l23};
        }
    }
}

// ---------------------------------------------------------------------------
extern "C" void kernel_launch(void* const* d_in, const int* in_sizes, int n_in,
                              void* d_out, int out_size, void* d_ws, size_t ws_size,
                              hipStream_t stream) {
    const float* x      = (const float*)d_in[0];
    const float* w_qkv  = (const float*)d_in[1];
    const float* b_qkv  = (const float*)d_in[2];
    const float* w_proj = (const float*)d_in[3];
    const float* b_proj = (const float*)d_in[4];
    float* out = (float*)d_out;

    // ws (130 MB, < proven-safe 134 MB):
    //   [0..5NE_)        qh ql kh vh vl
    //   [5NE_..7NE_)     xh xl (phase 0-1)  -> aliased by oh ol (phase 2+)
    //   [7NE_..)         wqh wql (6.29M u16, phase 0-1) -> aliased by wph wpl
    u16* qh  = (u16*)d_ws;
    u16* ql  = qh + NE_;
    u16* kh  = ql + NE_;
    u16* vh  = kh + NE_;
    u16* vl  = vh + NE_;
    u16* xh  = vl + NE_;
    u16* xl  = xh + NE_;
    u16* wqh = xl + NE_;
    u16* wql = wqh + (size_t)3 * 1024 * 1024;
    u16* oh  = xh;                         // alias (x dead after QKV)
    u16* ol  = xl;
    u16* wph = wqh;                        // alias (wq dead after QKV)
    u16* wpl = wph + (size_t)1024 * 1024;

    // Phase 0: one-time conversions to hi/lo k32 images (4 KB tiles)
    convert_img<<<128 * 32, 256, 0, stream>>>(x, xh, xl);        // 4096 tiles
    convert_img<<<48 * 32, 256, 0, stream>>>(w_qkv, wqh, wql);   // 1536 tiles

    {   // Phase 1: QKV GEMM (128^2, dbuf, 2 blocks/CU): x @ w_qkv^T + b -> q/k/v
        dim3 grid(M_ / 128, (3 * E_) / 128);   // 64 x 24
        gemm_qkv<<<grid, 256, 0, stream>>>(xh, xl, wqh, wql,
                                           b_qkv, qh, ql, kh, vh, vl);
    }
    {   // Phase 2: attention (XCD-bh-swizzled 1D grid, KV dbuf)
        attn_mfma<<<1024, 256, 0, stream>>>(qh, ql, kh, vh, vl, oh, ol);
    }
    // Phase 2.5: convert w_proj (overwrites wq images)
    convert_img<<<16 * 32, 256, 0, stream>>>(w_proj, wph, wpl);  // 512 tiles
    {   // Phase 3: proj GEMM (128^2, dbuf, 2 blocks/CU)
        dim3 grid(M_ / 128, E_ / 128);         // 64 x 8
        gemm_proj<<<grid, 256, 0, stream>>>(oh, ol, wph, wpl, b_proj, out);
    }
}

// Round 11
// 413.545 us; speedup vs baseline: 1.0445x; 1.0445x over previous
//
#include <hip/hip_runtime.h>
#include <cstdint>
#include <cstddef>

// Problem constants
#define B_ 4
#define S_ 2048
#define E_ 1024
#define H_ 16
#define D_ 64
#define M_ (B_*S_)                        // 8192 tokens
#define NE_ ((size_t)B_*H_*S_*D_)         // 8388608 elements per q/k/v buffer

typedef unsigned int  u32;
typedef unsigned short u16;
typedef __attribute__((ext_vector_type(8))) short bf16x8;
typedef __attribute__((ext_vector_type(4))) float f32x4;
typedef __attribute__((ext_vector_type(2))) unsigned int u32x2;

// fp32 -> bf16 (round-to-nearest-even), finite inputs
__device__ __forceinline__ u16 f2bf(float x) {
    u32 u = __float_as_uint(x);
    u32 r = (u + 0x7FFFu + ((u >> 16) & 1u)) >> 16;
    return (u16)r;
}
__device__ __forceinline__ float bf2f(u16 h) { return __uint_as_float((u32)h << 16); }

// packed fp32x2 -> bf16x2 (RNE), single VOP3 instruction (T12 recipe)
__device__ __forceinline__ u32 cvtpk_bf16(float lo, float hi) {
    u32 r;
    asm("v_cvt_pk_bf16_f32 %0, %1, %2" : "=v"(r) : "v"(lo), "v"(hi));
    return r;
}

// async global->LDS 16B DMA: per-lane global addr, wave-uniform LDS base;
// HW writes lane i at ldsbase + i*16 (linear).
__device__ __forceinline__ void gload_lds16(const void* gsrc, void* lds) {
    __builtin_amdgcn_global_load_lds(
        (const __attribute__((address_space(1))) u32*)gsrc,
        (__attribute__((address_space(3))) u32*)lds, 16, 0, 0);
}

// ---------------------------------------------------------------------------
// TWO image formats:
//
// k64 tile (64x64, 8 KB) -- used for K and V (attn kernel):
//   offset = r*64 + ((c ^ (r&7))<<3) + (k&7),  c = k>>3.
//
// k32 tile (64 rows x 32 k, 4 KB) -- used for all GEMM operands
// (x, w_qkv, w_proj, o). BK=32 GEMM K-step:
//   l = r>>1,  s = (r&1)*4 + (k>>3),  ph = s ^ (l&7)
//   offset = l*64 + ph*8 + (k&7)
// Image array: [row-tile][k-tile(32, K=1024)] -> tile idx = rt*32+kt.
// ---------------------------------------------------------------------------

// ---------------------------------------------------------------------------
// convert fp32 matrix (rows x 1024, row-major) -> hi/lo k32 images.
// Handles TWO independent matrices in one launch (saves a launch gap):
// tiles [0, n1) -> img1, tiles [n1, n1+n2) -> img2.
// ---------------------------------------------------------------------------
__global__ __launch_bounds__(256)
void convert_img2(const float* __restrict__ s1, u16* __restrict__ dh1, u16* __restrict__ dl1, int n1,
                  const float* __restrict__ s2, u16* __restrict__ dh2, u16* __restrict__ dl2)
{
    int tile = blockIdx.x;
    const float* src; u16* dh; u16* dl;
    if (tile < n1) { src = s1; dh = dh1; dl = dl1; }
    else           { tile -= n1; src = s2; dh = dh2; dl = dl2; }
    const int rt = tile >> 5, kt = tile & 31;
    const size_t tb = (size_t)tile * 2048;         // u16 elements
    const int ci = threadIdx.x;                    // 0..255, 8 el each
    const int l  = ci >> 3;                        // line 0..31
    const int ph = ci & 7;                         // phys slot
    const int s  = ph ^ (l & 7);                   // logical slot
    const int r  = (l << 1) | (s >> 2);            // source row in tile
    const int k0 = (s & 3) << 3;                   // source k base
    const float* sp = src + ((size_t)(rt * 64 + r)) * 1024 + kt * 32 + k0;
    const float4 f0 = *(const float4*)sp;
    const float4 f1 = *(const float4*)(sp + 4);
    const float vals[8] = {f0.x, f0.y, f0.z, f0.w, f1.x, f1.y, f1.z, f1.w};
    __align__(16) short hs[8];
    __align__(16) short ls[8];
    #pragma unroll
    for (int j = 0; j < 8; ++j) {
        const u16 h = f2bf(vals[j]);
        hs[j] = (short)h;
        ls[j] = (short)f2bf(vals[j] - bf2f(h));
    }
    *(bf16x8*)(dh + tb + ci * 8) = *(const bf16x8*)hs;
    *(bf16x8*)(dl + tb + ci * 8) = *(const bf16x8*)ls;
}

// single-matrix variant (w_proj, phase 2.5)
__global__ __launch_bounds__(256)
void convert_img(const float* __restrict__ src, u16* __restrict__ dh, u16* __restrict__ dl)
{
    const int tile = blockIdx.x;
    const int rt = tile >> 5, kt = tile & 31;
    const size_t tb = (size_t)tile * 2048;
    const int ci = threadIdx.x;
    const int l  = ci >> 3;
    const int ph = ci & 7;
    const int s  = ph ^ (l & 7);
    const int r  = (l << 1) | (s >> 2);
    const int k0 = (s & 3) << 3;
    const float* sp = src + ((size_t)(rt * 64 + r)) * 1024 + kt * 32 + k0;
    const float4 f0 = *(const float4*)sp;
    const float4 f1 = *(const float4*)(sp + 4);
    const float vals[8] = {f0.x, f0.y, f0.z, f0.w, f1.x, f1.y, f1.z, f1.w};
    __align__(16) short hs[8];
    __align__(16) short ls[8];
    #pragma unroll
    for (int j = 0; j < 8; ++j) {
        const u16 h = f2bf(vals[j]);
        hs[j] = (short)h;
        ls[j] = (short)f2bf(vals[j] - bf2f(h));
    }
    *(bf16x8*)(dh + tb + ci * 8) = *(const bf16x8*)hs;
    *(bf16x8*)(dl + tb + ci * 8) = *(const bf16x8*)ls;
}

// ---------------------------------------------------------------------------
// QKV GEMM -- UNCHANGED (measured best: 128^2, BK=32, 4 waves, dbuf 64 KB,
// 2 blocks/CU, DMA-first, one barrier per K-tile, no swizzle -- default
// round-robin dispatch already pins A-panels bx==c (mod 8) per XCD).
// ---------------------------------------------------------------------------
__global__ __launch_bounds__(256, 2)
void gemm_qkv(const u16* __restrict__ AIh, const u16* __restrict__ AIl,
              const u16* __restrict__ BIh, const u16* __restrict__ BIl,
              const float* __restrict__ bias,
              u16* __restrict__ qh, u16* __restrict__ ql,
              u16* __restrict__ kh,
              u16* __restrict__ vh, u16* __restrict__ vl)
{
    __shared__ __align__(16) u16 sT[2][8][2048];   // 64 KB

    const int tid = threadIdx.x, lane = tid & 63, w = tid >> 6;  // 4 waves
    const int quad = lane >> 4, l15 = lane & 15;
    const int bx = blockIdx.x, by = blockIdx.y;
    const int m0  = bx * 128;
    const int n0  = by * 128;
    const int mt0 = bx * 2;                        // A row-tile base (64-row)
    const int nt0 = by * 2;                        // B row-tile base
    const int rw  = w >> 1;                        // 0..1: wave's 64-row slab
    const int cw  = w & 1;                         // 0..1: wave's 64-col slab

    const u16* srcq[8];
    #pragma unroll
    for (int it = 0; it < 8; ++it) {
        const int g = w * 8 + it;
        const int t = g >> 2, qtr = g & 3;
        const u16* img = (t < 2) ? AIh : (t < 4) ? AIl : (t < 6) ? BIh : BIl;
        const int rtile = ((t < 4) ? mt0 : nt0) + (t & 1);
        srcq[it] = img + (size_t)rtile * (32 * 2048) + qtr * 512 + lane * 8;
    }

    f32x4 acc[4][4];
    #pragma unroll
    for (int i = 0; i < 4; ++i)
        #pragma unroll
        for (int j = 0; j < 4; ++j)
            acc[i][j] = (f32x4){0.f, 0.f, 0.f, 0.f};

    // prologue: stage K-tile 0 into buffer 0
    #pragma unroll
    for (int it = 0; it < 8; ++it)
        gload_lds16(srcq[it], (char*)&sT[0][0][0] + (w * 8 + it) * 1024);
    __syncthreads();

    #pragma unroll 2
    for (int kt = 0; kt < 32; ++kt) {
        const int cur = kt & 1;
        if (kt < 31) {
            #pragma unroll
            for (int it = 0; it < 8; ++it)
                gload_lds16(srcq[it] + (size_t)(kt + 1) * 2048,
                            (char*)&sT[cur ^ 1][0][0] + (w * 8 + it) * 1024);
        }
        bf16x8 aH[4], aL[4], bH[4], bL[4];
        #pragma unroll
        for (int i = 0; i < 4; ++i) {
            const int r = i * 16 + l15, l = r >> 1;
            const int off = l * 64 + (((((r & 1) << 2) + quad) ^ (l & 7)) << 3);
            aH[i] = *(const bf16x8*)&sT[cur][rw][off];
            aL[i] = *(const bf16x8*)&sT[cur][2 + rw][off];
        }
        #pragma unroll
        for (int j = 0; j < 4; ++j) {
            const int r = j * 16 + l15, l = r >> 1;
            const int off = l * 64 + (((((r & 1) << 2) + quad) ^ (l & 7)) << 3);
            bH[j] = *(const bf16x8*)&sT[cur][4 + cw][off];
            bL[j] = *(const bf16x8*)&sT[cur][6 + cw][off];
        }
        __builtin_amdgcn_s_setprio(1);
        #pragma unroll
        for (int i = 0; i < 4; ++i)
            #pragma unroll
            for (int j = 0; j < 4; ++j) {
                acc[i][j] = __builtin_amdgcn_mfma_f32_16x16x32_bf16(aL[i], bH[j], acc[i][j], 0, 0, 0);
                acc[i][j] = __builtin_amdgcn_mfma_f32_16x16x32_bf16(aH[i], bL[j], acc[i][j], 0, 0, 0);
                acc[i][j] = __builtin_amdgcn_mfma_f32_16x16x32_bf16(aH[i], bH[j], acc[i][j], 0, 0, 0);
            }
        __builtin_amdgcn_s_setprio(0);
        __syncthreads();
    }

    // ---- epilogue (q natural+scaled; k hi-only k64 image; v k64 image) ----
    const int fbase = n0 + cw * 64;                // 64-aligned
    float bj[4];
    #pragma unroll
    for (int j = 0; j < 4; ++j) bj[j] = bias[fbase + j * 16 + l15];

    const int cR = fbase >> 10;                    // 0=q 1=k 2=v (uniform per wave)
    const int hh = (fbase >> 6) & 15;
    #pragma unroll
    for (int i = 0; i < 4; ++i)
        #pragma unroll
        for (int j = 0; j < 4; ++j)
            #pragma unroll
            for (int reg = 0; reg < 4; ++reg) {
                float val = acc[i][j][reg] + bj[j];
                const int m = m0 + rw * 64 + i * 16 + quad * 4 + reg;
                const int d = j * 16 + l15;
                const int bb = m >> 11, s = m & 2047;
                const int bh = bb * 16 + hh;
                // q scale = 0.125 * log2(e): softmax uses exp2 directly.
                if (cR == 0) val *= 0.18033688011112042f;
                const u16 h = f2bf(val);
                if (cR == 0) {
                    const u16 lo = f2bf(val - bf2f(h));
                    const size_t idx = ((size_t)bh * 2048 + s) * 64 + d;
                    qh[idx] = h; ql[idx] = lo;
                } else if (cR == 1) {
                    // k-lo not consumed (2-product QK) -> only hi written (k64 image)
                    const size_t tile = (size_t)bh * 32 + (s >> 6);
                    const int r = s & 63;
                    const size_t off = (tile << 12) + r * 64 + (((d >> 3) ^ (r & 7)) << 3) + (d & 7);
                    kh[off] = h;
                } else {
                    const u16 lo = f2bf(val - bf2f(h));
                    const size_t tile = (size_t)bh * 32 + (s >> 6);
                    const size_t off = (tile << 12) + d * 64 + ((((s & 63) >> 3) ^ (d & 7)) << 3) + (s & 7);
                    vh[off] = h; vl[off] = lo;
                }
            }
}

// ---------------------------------------------------------------------------
// proj GEMM -- REVERTED to the r9 256x128 8-wave config (measured ~40 us;
// the 128^2/2-per-CU variant cost ~11 us on total in round 10 -- for this
// small-N (8 B-panels) single-round GEMM the 8-wave shape wins).
// BM=256, BN=128, BK=32; dbuf 96 KB; single __syncthreads per K-tile;
// identity 2D grid; frag reads before DMA issue.
// ---------------------------------------------------------------------------
__global__ __launch_bounds__(512, 2)
void gemm_proj(const u16* __restrict__ AIh, const u16* __restrict__ AIl,
               const u16* __restrict__ BIh, const u16* __restrict__ BIl,
               const float* __restrict__ bias, float* __restrict__ Cout)
{
    __shared__ __align__(16) u16 sT[2][12][2048];  // 96 KB

    const int tid = threadIdx.x, lane = tid & 63, w = tid >> 6;  // 8 waves
    const int quad = lane >> 4, l15 = lane & 15;
    const int bx = blockIdx.x, by = blockIdx.y;
    const int m0  = bx * 256;
    const int n0  = by * 128;
    const int mt0 = bx * 4;                        // A row-tile base (64-row)
    const int nt0 = by * 2;                        // B row-tile base
    const int rw  = w >> 1;                        // 0..3: wave's 64-row slab
    const int cw  = w & 1;                         // 0..1: wave's 64-col slab

    const u16* srcq[6];
    #pragma unroll
    for (int it = 0; it < 6; ++it) {
        const int g = w * 6 + it;
        const int t = g >> 2, qtr = g & 3;
        const u16* img = (t < 4) ? AIh : (t < 8) ? AIl : (t < 10) ? BIh : BIl;
        const int rtile = (t < 8) ? (mt0 + (t & 3)) : (nt0 + (t & 1));
        srcq[it] = img + (size_t)rtile * (32 * 2048) + qtr * 512 + lane * 8;
    }

    f32x4 acc[4][4];
    #pragma unroll
    for (int i = 0; i < 4; ++i)
        #pragma unroll
        for (int j = 0; j < 4; ++j)
            acc[i][j] = (f32x4){0.f, 0.f, 0.f, 0.f};

    // prologue: stage K-tile 0 into buffer 0
    #pragma unroll
    for (int it = 0; it < 6; ++it)
        gload_lds16(srcq[it], (char*)&sT[0][0][0] + (w * 6 + it) * 1024);
    __syncthreads();

    #pragma unroll 2
    for (int kt = 0; kt < 32; ++kt) {
        const int cur = kt & 1;
        // ---- fragment loads FIRST (no vmem in flight -> no forced vmcnt) ----
        bf16x8 aH[4], aL[4], bH[4], bL[4];
        #pragma unroll
        for (int i = 0; i < 4; ++i) {
            const int r = i * 16 + l15, l = r >> 1;
            const int off = l * 64 + (((((r & 1) << 2) + quad) ^ (l & 7)) << 3);
            aH[i] = *(const bf16x8*)&sT[cur][rw][off];
            aL[i] = *(const bf16x8*)&sT[cur][4 + rw][off];
        }
        #pragma unroll
        for (int j = 0; j < 4; ++j) {
            const int r = j * 16 + l15, l = r >> 1;
            const int off = l * 64 + (((((r & 1) << 2) + quad) ^ (l & 7)) << 3);
            bH[j] = *(const bf16x8*)&sT[cur][8 + cw][off];
            bL[j] = *(const bf16x8*)&sT[cur][10 + cw][off];
        }
        // ---- issue next-tile DMA (overlaps the MFMA cluster below) ----
        if (kt < 31) {
            #pragma unroll
            for (int it = 0; it < 6; ++it)
                gload_lds16(srcq[it] + (size_t)(kt + 1) * 2048,
                            (char*)&sT[cur ^ 1][0][0] + (w * 6 + it) * 1024);
        }
        // ---- 48 MFMA ----
        __builtin_amdgcn_s_setprio(1);
        #pragma unroll
        for (int i = 0; i < 4; ++i)
            #pragma unroll
            for (int j = 0; j < 4; ++j) {
                acc[i][j] = __builtin_amdgcn_mfma_f32_16x16x32_bf16(aL[i], bH[j], acc[i][j], 0, 0, 0);
                acc[i][j] = __builtin_amdgcn_mfma_f32_16x16x32_bf16(aH[i], bL[j], acc[i][j], 0, 0, 0);
                acc[i][j] = __builtin_amdgcn_mfma_f32_16x16x32_bf16(aH[i], bH[j], acc[i][j], 0, 0, 0);
            }
        __builtin_amdgcn_s_setprio(0);
        __syncthreads();
    }

    // ---- epilogue: plain fp32 + bias ----
    const int fbase = n0 + cw * 64;
    float bj[4];
    #pragma unroll
    for (int j = 0; j < 4; ++j) bj[j] = bias[fbase + j * 16 + l15];
    #pragma unroll
    for (int i = 0; i < 4; ++i)
        #pragma unroll
        for (int j = 0; j < 4; ++j)
            #pragma unroll
            for (int reg = 0; reg < 4; ++reg) {
                const int m = m0 + rw * 64 + i * 16 + quad * 4 + reg;
                const int f = fbase + j * 16 + l15;
                Cout[(size_t)m * 1024 + f] = acc[i][j][reg] + bj[j];
            }
}

// ---------------------------------------------------------------------------
// MFMA flash attention -- UNCHANGED from round 10 (measured 159.1 us,
// FETCH 41 MB via the bh-grouped XCD swizzle; KV dbuf, one barrier/tile).
// ---------------------------------------------------------------------------
__global__ __launch_bounds__(256, 3)
void attn_mfma(const u16* __restrict__ qh, const u16* __restrict__ ql,
               const u16* __restrict__ kh,
               const u16* __restrict__ vh, const u16* __restrict__ vl,
               u16* __restrict__ oh, u16* __restrict__ ol)
{
    __shared__ __align__(16) u16 KV[2][3][4096];  // dbuf x {Khi Vthi Vtlo} 48 KB

    const int tid  = threadIdx.x;
    const int lane = tid & 63, w = tid >> 6;
    const int quad = lane >> 4, l15 = lane & 15;

    // XCD swizzle: flat = j*8 + c  ->  logical = c*128 + j
    const int flat = blockIdx.x;
    const int logical = (flat & 7) * 128 + (flat >> 3);
    const int bh = logical >> 4;                  // 0..63
    const int q0 = (logical & 15) * 128 + w * 32; // q-chunk * 128

    bf16x8 Qf[2][2][2];
    #pragma unroll
    for (int qs = 0; qs < 2; ++qs)
        #pragma unroll
        for (int kk = 0; kk < 2; ++kk) {
            const size_t idx = ((size_t)bh * S_ + q0 + qs * 16 + l15) * 64 + kk * 32 + quad * 8;
            Qf[qs][kk][0] = *(const bf16x8*)(qh + idx);
            Qf[qs][kk][1] = *(const bf16x8*)(ql + idx);
        }

    f32x4 O[2][4];
    float l_part[2] = {0.f, 0.f};
    #pragma unroll
    for (int qs = 0; qs < 2; ++qs)
        #pragma unroll
        for (int ds = 0; ds < 4; ++ds)
            O[qs][ds] = (f32x4){0.f, 0.f, 0.f, 0.f};

    const char* gk[3] = {(const char*)kh, (const char*)vh, (const char*)vl};

    // prologue: stage K-tile 0 into buffer 0
    {
        const size_t tb = ((size_t)bh * 32) << 13;
        #pragma unroll
        for (int a = 0; a < 3; ++a)
            #pragma unroll
            for (int it = 0; it < 2; ++it) {
                const int off = w * 2048 + it * 1024;
                gload_lds16(gk[a] + tb + off + lane * 16, (char*)&KV[0][a][0] + off);
            }
    }
    __syncthreads();

    for (int kt = 0; kt < S_ / 64; ++kt) {
        const int cur = kt & 1;

        // issue next-tile DMA into the other buffer (no wait here)
        if (kt < S_ / 64 - 1) {
            const size_t tb = (((size_t)bh * 32 + kt + 1) << 13);
            #pragma unroll
            for (int a = 0; a < 3; ++a)
                #pragma unroll
                for (int it = 0; it < 2; ++it) {
                    const int off = w * 2048 + it * 1024;
                    gload_lds16(gk[a] + tb + off + lane * 16,
                                (char*)&KV[cur ^ 1][a][0] + off);
                }
        }

        // ---- swapped QK:  Ssw[m=k][n=q],  init = -16*log2(e) (fixed max) ----
        f32x4 S[2][4];
        #pragma unroll
        for (int qs = 0; qs < 2; ++qs)
            #pragma unroll
            for (int ks = 0; ks < 4; ++ks)
                S[qs][ks] = (f32x4){-23.083120654223414f, -23.083120654223414f,
                                    -23.083120654223414f, -23.083120654223414f};

        __builtin_amdgcn_s_setprio(1);
        #pragma unroll
        for (int ks = 0; ks < 4; ++ks) {
            const int r = ks * 16 + l15;
            #pragma unroll
            for (int kk = 0; kk < 2; ++kk) {
                const int c = (kk * 4 + quad) ^ (r & 7);
                const bf16x8 Kh = *(const bf16x8*)&KV[cur][0][r * 64 + c * 8];
                #pragma unroll
                for (int qs = 0; qs < 2; ++qs) {
                    S[qs][ks] = __builtin_amdgcn_mfma_f32_16x16x32_bf16(Kh, Qf[qs][kk][1], S[qs][ks], 0, 0, 0);
                    S[qs][ks] = __builtin_amdgcn_mfma_f32_16x16x32_bf16(Kh, Qf[qs][kk][0], S[qs][ks], 0, 0, 0);
                }
            }
        }
        __builtin_amdgcn_s_setprio(0);

        // ---- softmax + in-register transpose to PV operand layout ----
        u32 PA[2][2][4];     // [qs][kk][word]
        #pragma unroll
        for (int qs = 0; qs < 2; ++qs) {
            float lsum = 0.f;
            u32 PK[4][2];
            #pragma unroll
            for (int ks = 0; ks < 4; ++ks) {
                const float p0 = __builtin_exp2f(S[qs][ks][0]);
                const float p1 = __builtin_exp2f(S[qs][ks][1]);
                const float p2 = __builtin_exp2f(S[qs][ks][2]);
                const float p3 = __builtin_exp2f(S[qs][ks][3]);
                lsum += (p0 + p1) + (p2 + p3);
                PK[ks][0] = cvtpk_bf16(p0, p1);
                PK[ks][1] = cvtpk_bf16(p2, p3);
            }
            l_part[qs] += lsum;
            #pragma unroll
            for (int kk = 0; kk < 2; ++kk) {
                const u32x2 t0 = __builtin_amdgcn_permlane32_swap(PK[2 * kk][0], PK[2 * kk + 1][0], false, false);
                const u32x2 w02 = __builtin_amdgcn_permlane16_swap(t0.x, t0.y, false, false);
                const u32x2 t1 = __builtin_amdgcn_permlane32_swap(PK[2 * kk][1], PK[2 * kk + 1][1], false, false);
                const u32x2 w13 = __builtin_amdgcn_permlane16_swap(t1.x, t1.y, false, false);
                PA[qs][kk][0] = w02.x;
                PA[qs][kk][1] = w13.x;
                PA[qs][kk][2] = w02.y;
                PA[qs][kk][3] = w13.y;
            }
        }

        // ---- swapped PV:  O^T += Vt x PA  (two products: Vlo, Vhi) ----
        __builtin_amdgcn_s_setprio(1);
        #pragma unroll
        for (int kk = 0; kk < 2; ++kk) {
            union { u32 w4[4]; bf16x8 v; } pu0, pu1;
            #pragma unroll
            for (int c = 0; c < 4; ++c) { pu0.w4[c] = PA[0][kk][c]; pu1.w4[c] = PA[1][kk][c]; }
            const bf16x8 paf[2] = {pu0.v, pu1.v};
            #pragma unroll
            for (int ds = 0; ds < 4; ++ds) {
                const int r = ds * 16 + l15;
                const int c = (kk * 4 + quad) ^ (r & 7);
                const bf16x8 Vh = *(const bf16x8*)&KV[cur][1][r * 64 + c * 8];
                const bf16x8 Vl = *(const bf16x8*)&KV[cur][2][r * 64 + c * 8];
                #pragma unroll
                for (int qs = 0; qs < 2; ++qs) {
                    O[qs][ds] = __builtin_amdgcn_mfma_f32_16x16x32_bf16(Vl, paf[qs], O[qs][ds], 0, 0, 0);
                    O[qs][ds] = __builtin_amdgcn_mfma_f32_16x16x32_bf16(Vh, paf[qs], O[qs][ds], 0, 0, 0);
                }
            }
        }
        __builtin_amdgcn_s_setprio(0);

        // ONE barrier per tile: implicit vmcnt(0) drains the kt+1 prefetch;
        // also publishes "all waves done reading cur" for the next overwrite.
        __syncthreads();
    }

    // ---- l reduction across quads ----
    float linv[2];
    #pragma unroll
    for (int qs = 0; qs < 2; ++qs) {
        float rs = l_part[qs];
        rs += __shfl_xor(rs, 16);
        rs += __shfl_xor(rs, 32);
        linv[qs] = 1.f / rs;
    }

    // ---- epilogue: lane holds O[d = ds*16+quad*4+reg][q = l15];
    //      write k32 image format (proj GEMM input) ----
    const int bb = bh >> 4, hh = bh & 15;
    #pragma unroll
    for (int qs = 0; qs < 2; ++qs) {
        const float inv = linv[qs];
        const int s = q0 + qs * 16 + l15;
        const int m = bb * 2048 + s;
        const int mt = m >> 6, r = m & 63;
        const int l = r >> 1;
        const size_t tb0 = ((size_t)(mt * 32 + hh * 2)) * 2048;
        #pragma unroll
        for (int ds = 0; ds < 4; ++ds) {
            const int d0 = ds * 16 + quad * 4;     // 4 consecutive d per thread
            const float v0 = O[qs][ds][0] * inv;
            const float v1 = O[qs][ds][1] * inv;
            const float v2 = O[qs][ds][2] * inv;
            const float v3 = O[qs][ds][3] * inv;
            const u32 h01 = cvtpk_bf16(v0, v1);
            const u32 h23 = cvtpk_bf16(v2, v3);
            const float r0 = v0 - bf2f((u16)h01);
            const float r1 = v1 - bf2f((u16)(h01 >> 16));
            const float r2 = v2 - bf2f((u16)h23);
            const float r3 = v3 - bf2f((u16)(h23 >> 16));
            const u32 l01 = cvtpk_bf16(r0, r1);
            const u32 l23 = cvtpk_bf16(r2, r3);
            const int c  = (d0 & 31) >> 3;
            const int ph = (((r & 1) << 2) + c) ^ (l & 7);
            const size_t off = tb0 + (size_t)(d0 >> 5) * 2048 + l * 64 + ph * 8 + (d0 & 7);
            *(u32x2*)(oh + off) = (u32x2){h01, h23};
            *(u32x2*)(ol + off) = (u32x2){l01, l23};
        }
    }
}

// ---------------------------------------------------------------------------
extern "C" void kernel_launch(void* const* d_in, const int* in_sizes, int n_in,
                              void* d_out, int out_size, void* d_ws, size_t ws_size,
                              hipStream_t stream) {
    const float* x      = (const float*)d_in[0];
    const float* w_qkv  = (const float*)d_in[1];
    const float* b_qkv  = (const float*)d_in[2];
    const float* w_proj = (const float*)d_in[3];
    const float* b_proj = (const float*)d_in[4];
    float* out = (float*)d_out;

    // ws (130 MB, < proven-safe 134 MB):
    //   [0..5NE_)        qh ql kh vh vl
    //   [5NE_..7NE_)     xh xl (phase 0-1)  -> aliased by oh ol (phase 2+)
    //   [7NE_..)         wqh wql (6.29M u16, phase 0-1) -> aliased by wph wpl
    u16* qh  = (u16*)d_ws;
    u16* ql  = qh + NE_;
    u16* kh  = ql + NE_;
    u16* vh  = kh + NE_;
    u16* vl  = vh + NE_;
    u16* xh  = vl + NE_;
    u16* xl  = xh + NE_;
    u16* wqh = xl + NE_;
    u16* wql = wqh + (size_t)3 * 1024 * 1024;
    u16* oh  = xh;                         // alias (x dead after QKV)
    u16* ol  = xl;
    u16* wph = wqh;                        // alias (wq dead after QKV)
    u16* wpl = wph + (size_t)1024 * 1024;

    // Phase 0: one-time conversions to hi/lo k32 images (x + w_qkv, 1 launch)
    convert_img2<<<128 * 32 + 48 * 32, 256, 0, stream>>>(
        x, xh, xl, 128 * 32, w_qkv, wqh, wql);

    {   // Phase 1: QKV GEMM (128^2, dbuf, 2 blocks/CU): x @ w_qkv^T + b -> q/k/v
        dim3 grid(M_ / 128, (3 * E_) / 128);   // 64 x 24
        gemm_qkv<<<grid, 256, 0, stream>>>(xh, xl, wqh, wql,
                                           b_qkv, qh, ql, kh, vh, vl);
    }
    {   // Phase 2: attention (XCD-bh-swizzled 1D grid, KV dbuf)
        attn_mfma<<<1024, 256, 0, stream>>>(qh, ql, kh, vh, vl, oh, ol);
    }
    // Phase 2.5: convert w_proj (overwrites wq images)
    convert_img<<<16 * 32, 256, 0, stream>>>(w_proj, wph, wpl);  // 512 tiles
    {   // Phase 3: proj GEMM (r9 256x128 8-wave config)
        dim3 grid(M_ / 256, E_ / 128);         // 32 x 8
        gemm_proj<<<grid, 512, 0, stream>>>(oh, ol, wph, wpl, b_proj, out);
    }
}